// Round 1
// baseline (9003.976 us; speedup 1.0000x reference)
//
#include <hip/hip_runtime.h>

typedef __bf16 bf16;
typedef __bf16 bf16x8 __attribute__((ext_vector_type(8)));
typedef float f32x4 __attribute__((ext_vector_type(4)));

#define AS1 __attribute__((address_space(1)))
#define AS3 __attribute__((address_space(3)))

__device__ __forceinline__ void glds16(const void* src, void* lds) {
  __builtin_amdgcn_global_load_lds((const AS1 unsigned*)src, (AS3 unsigned*)lds, 16, 0, 0);
}
__device__ __forceinline__ float sigm(float x) { return 1.f / (1.f + __expf(-x)); }
__device__ __forceinline__ float tanh_f(float x) {
  float ax = fabsf(x);
  float e = __expf(-2.f * ax);
  float t = (1.f - e) / (1.f + e);
  return x < 0.f ? -t : t;
}

// ---------------- generic C = act(A @ B^T + bias) GEMM, bf16 in, f32 acc ----
// A: M x K (lda), B: N x K (ldb), both bf16 row-major. 128x128 tile, BK=32.
template<bool OUT_BF, bool RELU, bool HAS_BIAS>
__global__ __launch_bounds__(256) void gemm_bt(
    const bf16* __restrict__ A, int lda,
    const bf16* __restrict__ B, int ldb,
    void* __restrict__ Cv, int ldc,
    const float* __restrict__ bias,
    int M, int N, int K)
{
  __shared__ __align__(16) char smA[8192];
  __shared__ __align__(16) char smB[8192];
  const int tid = threadIdx.x;
  const int l = tid & 63, w = tid >> 6;
  const int lo16 = l & 15, grp = l >> 4;
  const int m0 = blockIdx.x * 128, n0 = blockIdx.y * 128;
  const int wm = w & 1, wn = w >> 1;
  f32x4 acc[4][4] = {};
  for (int k0 = 0; k0 < K; k0 += 32) {
    // stage 8KB A + 8KB B; swizzled source so swizzled ds_read is conflict-lite
#pragma unroll
    for (int q = 0; q < 2; ++q) {
      const int c = w * 2 + q;
      const int alin = c * 1024 + l * 16;
      const int row = alin >> 6;
      const int sb = alin ^ (((row >> 1) & 3) << 4);
      const int kk = (sb & 63) >> 1;
      int ra = m0 + row; ra = ra < M ? ra : M - 1;
      glds16(A + (size_t)ra * lda + k0 + kk, smA + c * 1024);
      int rb = n0 + row; rb = rb < N ? rb : N - 1;
      glds16(B + (size_t)rb * ldb + k0 + kk, smB + c * 1024);
    }
    __syncthreads();
    bf16x8 af[4], bfr[4];
#pragma unroll
    for (int mi = 0; mi < 4; ++mi) {
      int row = wm * 64 + mi * 16 + lo16;
      int a = ((row << 6) | (grp << 4)) ^ (((row >> 1) & 3) << 4);
      af[mi] = *(const bf16x8*)(smA + a);
    }
#pragma unroll
    for (int ni = 0; ni < 4; ++ni) {
      int row = wn * 64 + ni * 16 + lo16;
      int a = ((row << 6) | (grp << 4)) ^ (((row >> 1) & 3) << 4);
      bfr[ni] = *(const bf16x8*)(smB + a);
    }
#pragma unroll
    for (int mi = 0; mi < 4; ++mi)
#pragma unroll
      for (int ni = 0; ni < 4; ++ni)
        acc[mi][ni] = __builtin_amdgcn_mfma_f32_16x16x32_bf16(af[mi], bfr[ni], acc[mi][ni], 0, 0, 0);
    __syncthreads();
  }
#pragma unroll
  for (int mi = 0; mi < 4; ++mi)
#pragma unroll
    for (int ni = 0; ni < 4; ++ni)
#pragma unroll
      for (int r = 0; r < 4; ++r) {
        int row = m0 + wm * 64 + mi * 16 + grp * 4 + r;
        int col = n0 + wn * 64 + ni * 16 + lo16;
        if (row < M && col < N) {
          float v = acc[mi][ni][r];
          if (HAS_BIAS) v += bias[col];
          if (RELU) v = v > 0.f ? v : 0.f;
          if (OUT_BF) ((bf16*)Cv)[(size_t)row * ldc + col] = (bf16)v;
          else        ((float*)Cv)[(size_t)row * ldc + col] = v;
        }
      }
}

// ---------------- small prep kernels ----------------------------------------
__global__ void conv_bf(const float* __restrict__ s, bf16* __restrict__ d, int n) {
  int i = blockIdx.x * 256 + threadIdx.x;
  if (i < n) d[i] = (bf16)s[i];
}

// projT[e*1024+h] = proj_W[h,e] (e<514), row 514 = proj_b
__global__ void build_projT(const float* __restrict__ projW, const float* __restrict__ projb,
                            bf16* __restrict__ pT) {
  int i = blockIdx.x * 256 + threadIdx.x;
  if (i >= 515 * 1024) return;
  int e = i >> 10, h = i & 1023;
  float v = (e < 514) ? projW[h * 514 + e] : projb[h];
  pT[i] = (bf16)v;
}

// split Wfused (4096 x 520-padded, 515 valid cols) into bf16 emb-part + f32 coeffs
__global__ void wf_split(const float* __restrict__ wfused, const float* __restrict__ bih,
                         const float* __restrict__ bhh, float* __restrict__ wD,
                         float* __restrict__ wV, float* __restrict__ bias4) {
  int n = blockIdx.x * 256 + threadIdx.x;
  if (n >= 4096) return;
  wD[n] = wfused[(size_t)n * 520 + 512];
  wV[n] = wfused[(size_t)n * 520 + 513];
  bias4[n] = wfused[(size_t)n * 520 + 514] + bih[n] + bhh[n];
}
__global__ void wfe_conv(const float* __restrict__ wfused, bf16* __restrict__ wfe) {
  int i = blockIdx.x * 256 + threadIdx.x;
  if (i >= 4096 * 512) return;
  int n = i >> 9, e = i & 511;
  wfe[i] = (bf16)wfused[(size_t)n * 520 + e];
}

// W_hh -> MFMA B-fragment order: idx = ((((ng*4+g)*2+kh)*16+q)*2+nf)*64 + lane
__global__ void prep_warr(const float* __restrict__ whh, bf16* __restrict__ warr) {
  int idx = blockIdx.x * 256 + threadIdx.x;
  if (idx >= 524288) return;
  int lx = idx & 63;
  int rest = idx >> 6;
  int nf = rest & 1; rest >>= 1;
  int q = rest & 15; rest >>= 4;
  int kh = rest & 1; rest >>= 1;
  int gg = rest & 3; rest >>= 2;
  int ng = rest;  // 0..31
  int row = gg * 1024 + ng * 32 + nf * 16 + (lx & 15);
  int kb = (q * 2 + kh) * 32 + (lx >> 4) * 8;
  bf16* dst = warr + (size_t)idx * 8;
  const float* src = whh + (size_t)row * 1024 + kb;
#pragma unroll
  for (int j = 0; j < 8; ++j) dst[j] = (bf16)src[j];
}

__global__ void build_tin(const float* __restrict__ hstate, const float* __restrict__ statef,
                          bf16* __restrict__ tin) {
  int i = blockIdx.x * 256 + threadIdx.x;
  if (i >= 256 * 1088) return;
  int b = i / 1088, k = i % 1088;
  float v = (k < 1024) ? hstate[b * 1024 + k] : statef[b * 64 + (k - 1024)];
  tin[i] = (bf16)v;
}

__global__ void delta_head(const bf16* __restrict__ t2, const float* __restrict__ delW,
                           const float* __restrict__ delb, float* __restrict__ out) {
  int b = threadIdx.x;
  float s = 0.f;
  for (int k = 0; k < 1024; ++k) s += (float)t2[b * 1024 + k] * delW[k];
  out[b] = s + delb[0];
}

__global__ void sentinel(float* out) { out[0] = 1e30f; }

// ---------------- persistent LSTM scan --------------------------------------
// 256 blocks x 512 threads. Block (bg,ng) owns rows [bg*32,+32), h-cols [ng*32,+32).
// W_hh slice lives in registers (32 bf16x8 frags/lane). h,c in registers.
// 8 independent row-group barriers (32 blocks each).
__global__ __launch_bounds__(512, 2) void scan_kernel(
    const bf16* __restrict__ embg,    // [10000][4096]
    const bf16* __restrict__ warr,
    const float* __restrict__ wfD, const float* __restrict__ wfV, const float* __restrict__ bias4,
    const int* __restrict__ labels, const float* __restrict__ deltas, const int* __restrict__ lengths,
    const float* __restrict__ decW, const float* __restrict__ decb,
    bf16* __restrict__ hpre0, bf16* __restrict__ hpre1,  // double-buffered decayed h (bf16)
    float* __restrict__ hstate, int* __restrict__ bar)
{
  __shared__ __align__(16) char smh[65536];   // h tile 32x1024 bf16, XOR-swizzled
  __shared__ float smG[4][32][33];            // gate exchange
  __shared__ float s_dl0[32], s_dl1[32];
  __shared__ int s_lab[32];

  const int tid = threadIdx.x;
  const int l = tid & 63, w = tid >> 6;
  const int lo16 = l & 15, grp = l >> 4;
  const int wg = blockIdx.x;
  const int ng = (wg & 7) * 4 + ((wg >> 3) & 3);  // XCD-local n-slices
  const int bg = wg >> 5;
  const int b0 = bg * 32, n0 = ng * 32;
  const int g = w & 3, kh = w >> 2;   // wave = (gate, K-half)

  // preload W_hh fragments into registers (once)
  bf16x8 wf[32];
  {
    const bf16* wp = warr + ((size_t)((ng * 4 + g) * 2 + kh)) * 16384 + (size_t)l * 8;
#pragma unroll
    for (int qq = 0; qq < 32; ++qq) wf[qq] = *(const bf16x8*)(wp + (size_t)qq * 512);
  }

  const int r0 = tid >> 5;   // 0..15
  const int cc = tid & 31;
  const int len0 = lengths[b0 + r0];
  const int len1 = lengths[b0 + r0 + 16];
  const float decWc = decW[n0 + cc], decbc = decb[n0 + cc];
  float wDr[4], wVr[4], wBr[4];
#pragma unroll
  for (int gg = 0; gg < 4; ++gg) {
    int colx = gg * 1024 + n0 + cc;
    wDr[gg] = wfD[colx]; wVr[gg] = wfV[colx]; wBr[gg] = bias4[colx];
  }
  float c0 = 0.f, c1 = 0.f, h0 = 0.f, h1 = 0.f;
  int* mybar = bar + bg * 64;

#pragma unroll 1
  for (int t = 0; t < 512; ++t) {
    const bf16* hread = (t & 1) ? hpre1 : hpre0;
    bf16* hwrite = (t & 1) ? hpre0 : hpre1;
    // phase 1: stage scalars + h tile
    if (tid < 32) s_dl0[tid] = log1pf(deltas[(b0 + tid) * 512 + t]);
    else if (tid < 64) { int i = tid - 32; s_dl1[i] = (t + 1 < 512) ? log1pf(deltas[(b0 + i) * 512 + t + 1]) : 0.f; }
    else if (tid < 96) { int i = tid - 64; s_lab[i] = labels[(b0 + i) * 512 + t]; }
    if (t > 0) {
#pragma unroll
      for (int q = 0; q < 8; ++q) {
        int ch = w * 8 + q;
        int a = ch * 1024 + l * 16;
        int row = a >> 11;
        int sb = a ^ ((row & 7) << 4);  // pre-swizzled source, linear LDS dest
        glds16(hread + (size_t)(b0 + row) * 1024 + ((sb & 2047) >> 1), smh + ch * 1024);
      }
    }
    __syncthreads();
    // phase 2: prefetch EMBG gather (hidden under MFMA)
    float eg[2][4];
#pragma unroll
    for (int j = 0; j < 2; ++j) {
      int lb = s_lab[r0 + j * 16];
#pragma unroll
      for (int gg = 0; gg < 4; ++gg)
        eg[j][gg] = (float)embg[(size_t)lb * 4096 + gg * 1024 + n0 + cc];
    }
    // phase 3: MFMA  (gate tile 32x32, this wave's K-half)
    f32x4 a00 = {}, a01 = {}, a10 = {}, a11 = {};
    if (t > 0) {
#pragma unroll
      for (int q = 0; q < 16; ++q) {
        const int kf = q * 2 + kh;
        {
          int row = lo16;
          int a = ((row << 11) | (kf << 6) | (grp << 4)) ^ ((row & 7) << 4);
          bf16x8 af = *(const bf16x8*)(smh + a);
          a00 = __builtin_amdgcn_mfma_f32_16x16x32_bf16(af, wf[q * 2 + 0], a00, 0, 0, 0);
          a01 = __builtin_amdgcn_mfma_f32_16x16x32_bf16(af, wf[q * 2 + 1], a01, 0, 0, 0);
        }
        {
          int row = 16 + lo16;
          int a = ((row << 11) | (kf << 6) | (grp << 4)) ^ ((row & 7) << 4);
          bf16x8 af = *(const bf16x8*)(smh + a);
          a10 = __builtin_amdgcn_mfma_f32_16x16x32_bf16(af, wf[q * 2 + 0], a10, 0, 0, 0);
          a11 = __builtin_amdgcn_mfma_f32_16x16x32_bf16(af, wf[q * 2 + 1], a11, 0, 0, 0);
        }
      }
    }
    __syncthreads();
    if (kh == 0) {
#pragma unroll
      for (int r = 0; r < 4; ++r) {
        smG[g][grp * 4 + r][lo16]        = a00[r];
        smG[g][grp * 4 + r][16 + lo16]   = a01[r];
        smG[g][16 + grp * 4 + r][lo16]      = a10[r];
        smG[g][16 + grp * 4 + r][16 + lo16] = a11[r];
      }
    }
    __syncthreads();
    if (kh == 1) {
#pragma unroll
      for (int r = 0; r < 4; ++r) {
        smG[g][grp * 4 + r][lo16]        += a00[r];
        smG[g][grp * 4 + r][16 + lo16]   += a01[r];
        smG[g][16 + grp * 4 + r][lo16]      += a10[r];
        smG[g][16 + grp * 4 + r][16 + lo16] += a11[r];
      }
    }
    __syncthreads();
    // phase 4: LSTM elementwise, 2 cells/thread
#pragma unroll
    for (int j = 0; j < 2; ++j) {
      const int rr = r0 + j * 16;
      float dl0 = s_dl0[rr];
      const int len = j ? len1 : len0;
      const bool valid = t < len;
      float zi = smG[0][rr][cc] + eg[j][0] + dl0 * wDr[0] + (valid ? wVr[0] : 0.f) + wBr[0];
      float zf = smG[1][rr][cc] + eg[j][1] + dl0 * wDr[1] + (valid ? wVr[1] : 0.f) + wBr[1];
      float zg = smG[2][rr][cc] + eg[j][2] + dl0 * wDr[2] + (valid ? wVr[2] : 0.f) + wBr[2];
      float zo = smG[3][rr][cc] + eg[j][3] + dl0 * wDr[3] + (valid ? wVr[3] : 0.f) + wBr[3];
      float cprev = j ? c1 : c0;
      float hprev = j ? h1 : h0;
      float gam = sigm(dl0 * decWc + decbc);
      float hdec = hprev * gam;
      float nc = sigm(zf) * cprev + sigm(zi) * tanh_f(zg);
      float nh = sigm(zo) * tanh_f(nc);
      float hn = valid ? nh : hdec;
      float cn = valid ? nc : cprev;
      if (j) { c1 = cn; h1 = hn; } else { c0 = cn; h0 = hn; }
      if (t < 511) {
        float g1 = sigm(s_dl1[rr] * decWc + decbc);
        hwrite[(size_t)(b0 + rr) * 1024 + n0 + cc] = (bf16)(hn * g1);
      } else {
        hstate[(size_t)(b0 + rr) * 1024 + n0 + cc] = hn;
      }
    }
    // phase 5: row-group barrier (32 blocks sharing bg)
    if (t < 511) {
      __syncthreads();
      if (tid == 0) {
        __threadfence();
        __hip_atomic_fetch_add(mybar, 1, __ATOMIC_RELEASE, __HIP_MEMORY_SCOPE_AGENT);
        const int target = 32 * (t + 1);
        while (__hip_atomic_load(mybar, __ATOMIC_ACQUIRE, __HIP_MEMORY_SCOPE_AGENT) < target)
          __builtin_amdgcn_s_sleep(4);
      }
      __syncthreads();
    }
  }
}

// ---------------- host -------------------------------------------------------
extern "C" void kernel_launch(void* const* d_in, const int* in_sizes, int n_in,
                              void* d_out, int out_size, void* d_ws, size_t ws_size,
                              hipStream_t stream) {
  const int*   labels = (const int*)d_in[0];
  const float* deltas = (const float*)d_in[1];
  const int*   lengths= (const int*)d_in[2];
  const float* statef = (const float*)d_in[3];
  const float* emb    = (const float*)d_in[4];
  const float* projW  = (const float*)d_in[5];
  const float* projb  = (const float*)d_in[6];
  const float* decW   = (const float*)d_in[7];
  const float* decb   = (const float*)d_in[8];
  const float* wih    = (const float*)d_in[9];
  const float* whh    = (const float*)d_in[10];
  const float* bih    = (const float*)d_in[11];
  const float* bhh    = (const float*)d_in[12];
  const float* sh1W   = (const float*)d_in[13];
  const float* sh1b   = (const float*)d_in[14];
  const float* sh2W   = (const float*)d_in[15];
  const float* sh2b   = (const float*)d_in[16];
  const float* labW   = (const float*)d_in[17];
  const float* labb   = (const float*)d_in[18];
  const float* delW   = (const float*)d_in[19];
  const float* delb   = (const float*)d_in[20];

  char* ws = (char*)d_ws;
  size_t off = 0;
  auto alloc = [&](size_t bytes) -> void* {
    void* p = ws + off;
    off += (bytes + 1023) & ~(size_t)1023;
    return p;
  };
  bf16*  emb_bf  = (bf16*)alloc((size_t)10000 * 512 * 2);
  bf16*  projT   = (bf16*)alloc((size_t)515 * 1024 * 2);
  bf16*  wih_bf  = (bf16*)alloc((size_t)4096 * 1024 * 2);
  float* wfused  = (float*)alloc((size_t)4096 * 520 * 4);
  bf16*  wfe     = (bf16*)alloc((size_t)4096 * 512 * 2);
  float* wfD     = (float*)alloc(4096 * 4);
  float* wfV     = (float*)alloc(4096 * 4);
  float* bias4   = (float*)alloc(4096 * 4);
  bf16*  embg    = (bf16*)alloc((size_t)10000 * 4096 * 2);
  bf16*  warr    = (bf16*)alloc((size_t)4096 * 1024 * 2);
  bf16*  hpre0   = (bf16*)alloc((size_t)256 * 1024 * 2);
  bf16*  hpre1   = (bf16*)alloc((size_t)256 * 1024 * 2);
  float* hstate  = (float*)alloc((size_t)256 * 1024 * 4);
  bf16*  tin     = (bf16*)alloc((size_t)256 * 1088 * 2);
  bf16*  t1      = (bf16*)alloc((size_t)256 * 1024 * 2);
  bf16*  t2      = (bf16*)alloc((size_t)256 * 1024 * 2);
  bf16*  sh1w_bf = (bf16*)alloc((size_t)1024 * 1088 * 2);
  bf16*  sh2w_bf = (bf16*)alloc((size_t)1024 * 1024 * 2);
  bf16*  labw_bf = (bf16*)alloc((size_t)10000 * 1024 * 2);
  int*   bar     = (int*)alloc(2048);

  if (off > ws_size) {
    sentinel<<<1, 1, 0, stream>>>((float*)d_out);
    return;
  }

  // prep: bf16 conversions + fused weights
  conv_bf<<<(5120000 + 255) / 256, 256, 0, stream>>>(emb, emb_bf, 5120000);
  build_projT<<<(515 * 1024 + 255) / 256, 256, 0, stream>>>(projW, projb, projT);
  conv_bf<<<(4194304 + 255) / 256, 256, 0, stream>>>(wih, wih_bf, 4194304);
  gemm_bt<false, false, false><<<dim3(32, 5), 256, 0, stream>>>(
      wih_bf, 1024, projT, 1024, (void*)wfused, 520, nullptr, 4096, 515, 1024);
  wf_split<<<16, 256, 0, stream>>>(wfused, bih, bhh, wfD, wfV, bias4);
  wfe_conv<<<(4096 * 512 + 255) / 256, 256, 0, stream>>>(wfused, wfe);
  gemm_bt<true, false, false><<<dim3(79, 32), 256, 0, stream>>>(
      emb_bf, 512, wfe, 512, (void*)embg, 4096, nullptr, 10000, 4096, 512);
  prep_warr<<<(524288 + 255) / 256, 256, 0, stream>>>(whh, warr);
  conv_bf<<<(1114112 + 255) / 256, 256, 0, stream>>>(sh1W, sh1w_bf, 1114112);
  conv_bf<<<(1048576 + 255) / 256, 256, 0, stream>>>(sh2W, sh2w_bf, 1048576);
  conv_bf<<<(10240000 + 255) / 256, 256, 0, stream>>>(labW, labw_bf, 10240000);

  // scan
  hipMemsetAsync(bar, 0, 2048, stream);
  scan_kernel<<<256, 512, 0, stream>>>(embg, warr, wfD, wfV, bias4,
                                       labels, deltas, lengths, decW, decb,
                                       hpre0, hpre1, hstate, bar);

  // head
  build_tin<<<(256 * 1088 + 255) / 256, 256, 0, stream>>>(hstate, statef, tin);
  gemm_bt<true, true, true><<<dim3(2, 8), 256, 0, stream>>>(
      tin, 1088, sh1w_bf, 1088, (void*)t1, 1024, sh1b, 256, 1024, 1088);
  gemm_bt<true, true, true><<<dim3(2, 8), 256, 0, stream>>>(
      t1, 1024, sh2w_bf, 1024, (void*)t2, 1024, sh2b, 256, 1024, 1024);
  gemm_bt<false, false, true><<<dim3(2, 79), 256, 0, stream>>>(
      t2, 1024, labw_bf, 1024, d_out, 10000, labb, 256, 10000, 1024);
  delta_head<<<1, 256, 0, stream>>>(t2, delW, delb, (float*)d_out + 2560000);
}

// Round 2
// 3246.563 us; speedup vs baseline: 2.7734x; 2.7734x over previous
//
#include <hip/hip_runtime.h>

typedef __bf16 bf16;
typedef __bf16 bf16x8 __attribute__((ext_vector_type(8)));
typedef float f32x4 __attribute__((ext_vector_type(4)));

#define AS1 __attribute__((address_space(1)))
#define AS3 __attribute__((address_space(3)))

__device__ __forceinline__ void glds16(const void* src, void* lds) {
  __builtin_amdgcn_global_load_lds((const AS1 unsigned*)src, (AS3 unsigned*)lds, 16, 0, 0);
}
__device__ __forceinline__ float sigm(float x) { return 1.f / (1.f + __expf(-x)); }
__device__ __forceinline__ float tanh_f(float x) {
  float ax = fabsf(x);
  float e = __expf(-2.f * ax);
  float t = (1.f - e) / (1.f + e);
  return x < 0.f ? -t : t;
}
__device__ __forceinline__ float bits2f(unsigned u) {
  union { unsigned u; float f; } c; c.u = u; return c.f;
}

// ---------------- generic C = act(A @ B^T + bias) GEMM, bf16 in, f32 acc ----
template<bool OUT_BF, bool RELU, bool HAS_BIAS>
__global__ __launch_bounds__(256) void gemm_bt(
    const bf16* __restrict__ A, int lda,
    const bf16* __restrict__ B, int ldb,
    void* __restrict__ Cv, int ldc,
    const float* __restrict__ bias,
    int M, int N, int K)
{
  __shared__ __align__(16) char smA[8192];
  __shared__ __align__(16) char smB[8192];
  const int tid = threadIdx.x;
  const int l = tid & 63, w = tid >> 6;
  const int lo16 = l & 15, grp = l >> 4;
  const int m0 = blockIdx.x * 128, n0 = blockIdx.y * 128;
  const int wm = w & 1, wn = w >> 1;
  f32x4 acc[4][4] = {};
  for (int k0 = 0; k0 < K; k0 += 32) {
#pragma unroll
    for (int q = 0; q < 2; ++q) {
      const int c = w * 2 + q;
      const int alin = c * 1024 + l * 16;
      const int row = alin >> 6;
      const int sb = alin ^ (((row >> 1) & 3) << 4);
      const int kk = (sb & 63) >> 1;
      int ra = m0 + row; ra = ra < M ? ra : M - 1;
      glds16(A + (size_t)ra * lda + k0 + kk, smA + c * 1024);
      int rb = n0 + row; rb = rb < N ? rb : N - 1;
      glds16(B + (size_t)rb * ldb + k0 + kk, smB + c * 1024);
    }
    __syncthreads();
    bf16x8 af[4], bfr[4];
#pragma unroll
    for (int mi = 0; mi < 4; ++mi) {
      int row = wm * 64 + mi * 16 + lo16;
      int a = ((row << 6) | (grp << 4)) ^ (((row >> 1) & 3) << 4);
      af[mi] = *(const bf16x8*)(smA + a);
    }
#pragma unroll
    for (int ni = 0; ni < 4; ++ni) {
      int row = wn * 64 + ni * 16 + lo16;
      int a = ((row << 6) | (grp << 4)) ^ (((row >> 1) & 3) << 4);
      bfr[ni] = *(const bf16x8*)(smB + a);
    }
#pragma unroll
    for (int mi = 0; mi < 4; ++mi)
#pragma unroll
      for (int ni = 0; ni < 4; ++ni)
        acc[mi][ni] = __builtin_amdgcn_mfma_f32_16x16x32_bf16(af[mi], bfr[ni], acc[mi][ni], 0, 0, 0);
    __syncthreads();
  }
#pragma unroll
  for (int mi = 0; mi < 4; ++mi)
#pragma unroll
    for (int ni = 0; ni < 4; ++ni)
#pragma unroll
      for (int r = 0; r < 4; ++r) {
        int row = m0 + wm * 64 + mi * 16 + grp * 4 + r;
        int col = n0 + wn * 64 + ni * 16 + lo16;
        if (row < M && col < N) {
          float v = acc[mi][ni][r];
          if (HAS_BIAS) v += bias[col];
          if (RELU) v = v > 0.f ? v : 0.f;
          if (OUT_BF) ((bf16*)Cv)[(size_t)row * ldc + col] = (bf16)v;
          else        ((float*)Cv)[(size_t)row * ldc + col] = v;
        }
      }
}

// ---------------- small prep kernels ----------------------------------------
__global__ void conv_bf(const float* __restrict__ s, bf16* __restrict__ d, int n) {
  int i = blockIdx.x * 256 + threadIdx.x;
  if (i < n) d[i] = (bf16)s[i];
}

__global__ void dlog_prep(const float* __restrict__ deltas, float* __restrict__ dlog, int n) {
  int i = blockIdx.x * 256 + threadIdx.x;
  if (i < n) dlog[i] = log1pf(deltas[i]);
}

__global__ void build_projT(const float* __restrict__ projW, const float* __restrict__ projb,
                            bf16* __restrict__ pT) {
  int i = blockIdx.x * 256 + threadIdx.x;
  if (i >= 515 * 1024) return;
  int e = i >> 10, h = i & 1023;
  float v = (e < 514) ? projW[h * 514 + e] : projb[h];
  pT[i] = (bf16)v;
}

__global__ void wf_split(const float* __restrict__ wfused, const float* __restrict__ bih,
                         const float* __restrict__ bhh, float* __restrict__ wD,
                         float* __restrict__ wV, float* __restrict__ bias4) {
  int n = blockIdx.x * 256 + threadIdx.x;
  if (n >= 4096) return;
  wD[n] = wfused[(size_t)n * 520 + 512];
  wV[n] = wfused[(size_t)n * 520 + 513];
  bias4[n] = wfused[(size_t)n * 520 + 514] + bih[n] + bhh[n];
}
__global__ void wfe_conv(const float* __restrict__ wfused, bf16* __restrict__ wfe) {
  int i = blockIdx.x * 256 + threadIdx.x;
  if (i >= 4096 * 512) return;
  int n = i >> 9, e = i & 511;
  wfe[i] = (bf16)wfused[(size_t)n * 520 + e];
}

__global__ void prep_warr(const float* __restrict__ whh, bf16* __restrict__ warr) {
  int idx = blockIdx.x * 256 + threadIdx.x;
  if (idx >= 524288) return;
  int lx = idx & 63;
  int rest = idx >> 6;
  int nf = rest & 1; rest >>= 1;
  int q = rest & 15; rest >>= 4;
  int kh = rest & 1; rest >>= 1;
  int gg = rest & 3; rest >>= 2;
  int ng = rest;
  int row = gg * 1024 + ng * 32 + nf * 16 + (lx & 15);
  int kb = (q * 2 + kh) * 32 + (lx >> 4) * 8;
  bf16* dst = warr + (size_t)idx * 8;
  const float* src = whh + (size_t)row * 1024 + kb;
#pragma unroll
  for (int j = 0; j < 8; ++j) dst[j] = (bf16)src[j];
}

__global__ void build_tin(const float* __restrict__ hstate, const float* __restrict__ statef,
                          bf16* __restrict__ tin) {
  int i = blockIdx.x * 256 + threadIdx.x;
  if (i >= 256 * 1088) return;
  int b = i / 1088, k = i % 1088;
  float v = (k < 1024) ? hstate[b * 1024 + k] : statef[b * 64 + (k - 1024)];
  tin[i] = (bf16)v;
}

__global__ void delta_head(const bf16* __restrict__ t2, const float* __restrict__ delW,
                           const float* __restrict__ delb, float* __restrict__ out) {
  int b = threadIdx.x;
  float s = 0.f;
  for (int k = 0; k < 1024; ++k) s += (float)t2[b * 1024 + k] * delW[k];
  out[b] = s + delb[0];
}

__global__ void sentinel(float* out) { out[0] = 1e30f; }

// ---------------- persistent LSTM scan (v2: fence-free coherence) -----------
// 256 blocks x 512 threads. Block (bg,ng): rows [bg*32,+32), h-cols [ng*32,+32).
// h exchange: sc0 sc1 point-coherent loads/stores (no L2 invalidate/writeback).
// Barrier: per-(bg,ng) flag word + relaxed polls (no atomics, no fences).
__global__ __launch_bounds__(512, 1) void scan_kernel(
    const bf16* __restrict__ embg,
    const bf16* __restrict__ warr,
    const float* __restrict__ wfD, const float* __restrict__ wfV, const float* __restrict__ bias4,
    const int* __restrict__ labels, const float* __restrict__ dlog, const int* __restrict__ lengths,
    const float* __restrict__ decW, const float* __restrict__ decb,
    bf16* __restrict__ hpre0, bf16* __restrict__ hpre1,
    float* __restrict__ hstate, int* __restrict__ flags)
{
  __shared__ __align__(16) char smh[65536];     // 32 x 2048B h tile, XOR-swizzled
  __shared__ float smG[2][4][32][34];           // gate partials per K-half
  __shared__ float s_dl0[32], s_dl1[32];
  __shared__ int s_lab[32];

  const int tid = threadIdx.x;
  const int l = tid & 63, w = tid >> 6;
  const int lo16 = l & 15, grp = l >> 4;
  const int wg = blockIdx.x;
  const int ng = wg & 31, bg = wg >> 5;
  const int b0 = bg * 32, n0 = ng * 32;
  const int g = w & 3, kh = w >> 2;

  // W_hh fragments -> registers (once)
  bf16x8 wf[32];
  {
    const bf16* wp = warr + ((size_t)((ng * 4 + g) * 2 + kh)) * 16384 + (size_t)l * 8;
#pragma unroll
    for (int qq = 0; qq < 32; ++qq) wf[qq] = *(const bf16x8*)(wp + (size_t)qq * 512);
  }

  // elementwise mapping: thread -> (row, col-pair)
  const int row = tid >> 4;        // 0..31
  const int cp = tid & 15;         // 0..15
  const int c0 = cp * 2;
  const int len = lengths[b0 + row];
  const float dW0 = decW[n0 + c0], dW1 = decW[n0 + c0 + 1];
  const float dB0 = decb[n0 + c0], dB1 = decb[n0 + c0 + 1];
  float wD[4][2], wV[4][2], wB[4][2];
#pragma unroll
  for (int gg = 0; gg < 4; ++gg) {
    int cx = gg * 1024 + n0 + c0;
    wD[gg][0] = wfD[cx]; wD[gg][1] = wfD[cx + 1];
    wV[gg][0] = wfV[cx]; wV[gg][1] = wfV[cx + 1];
    wB[gg][0] = bias4[cx]; wB[gg][1] = bias4[cx + 1];
  }
  float cc0 = 0.f, cc1 = 0.f, hh0 = 0.f, hh1 = 0.f;
  int* grpflags = flags + bg * 32;

#pragma unroll 1
  for (int t = 0; t < 512; ++t) {
    const bf16* hread = (t & 1) ? hpre1 : hpre0;
    bf16* hwrite = (t & 1) ? hpre0 : hpre1;

    if (tid < 32) s_lab[tid] = labels[(b0 + tid) * 512 + t];
    else if (tid < 64) { int i = tid - 32; s_dl0[i] = dlog[(b0 + i) * 512 + t]; }
    else if (tid < 96) { int i = tid - 64; s_dl1[i] = (t + 1 < 512) ? dlog[(b0 + i) * 512 + t + 1] : 0.f; }

    if (t > 0) {
      // stage h: coherent 16B loads -> regs -> swizzled ds_write (coalesced 1KB/wave/instr)
      f32x4 stg[8];
#pragma unroll
      for (int q = 0; q < 8; ++q) {
        const int r_ = 4 * w + (q >> 1);
        const int cb = (q & 1) * 1024 + l * 16;
        const char* src = (const char*)hread + (size_t)(b0 + r_) * 2048 + cb;
        asm volatile("global_load_dwordx4 %0, %1, off sc0 sc1" : "=v"(stg[q]) : "v"(src));
      }
      asm volatile("s_waitcnt vmcnt(0)" ::: "memory");
      __builtin_amdgcn_sched_barrier(0);
#pragma unroll
      for (int q = 0; q < 8; ++q) {
        const int r_ = 4 * w + (q >> 1);
        const int a = r_ * 2048 + (q & 1) * 1024 + l * 16;
        *(f32x4*)(smh + (a ^ ((r_ & 7) << 4))) = stg[q];
      }
    }
    __syncthreads();

    // embg gather (L2-cached; overlaps MFMA)
    float eg[4][2];
    {
      const int lb = s_lab[row];
      const char* base = (const char*)embg + ((size_t)lb * 4096 + n0 + c0) * 2;
#pragma unroll
      for (int gg = 0; gg < 4; ++gg) {
        unsigned u = *(const unsigned*)(base + gg * 2048);
        eg[gg][0] = bits2f(u << 16);
        eg[gg][1] = bits2f(u & 0xffff0000u);
      }
    }

    // MFMA: this wave = (gate g, K-half kh); 32x32 gate tile over K=1024
    f32x4 a00 = {}, a01 = {}, a10 = {}, a11 = {};
    if (t > 0) {
#pragma unroll
      for (int q = 0; q < 16; ++q) {
        const int kf = q * 2 + kh;
        {
          const int ar = lo16;
          const int a = ((ar << 11) | (kf << 6) | (grp << 4)) ^ ((ar & 7) << 4);
          bf16x8 af = *(const bf16x8*)(smh + a);
          a00 = __builtin_amdgcn_mfma_f32_16x16x32_bf16(af, wf[q * 2 + 0], a00, 0, 0, 0);
          a01 = __builtin_amdgcn_mfma_f32_16x16x32_bf16(af, wf[q * 2 + 1], a01, 0, 0, 0);
        }
        {
          const int ar = 16 + lo16;
          const int a = ((ar << 11) | (kf << 6) | (grp << 4)) ^ ((ar & 7) << 4);
          bf16x8 af = *(const bf16x8*)(smh + a);
          a10 = __builtin_amdgcn_mfma_f32_16x16x32_bf16(af, wf[q * 2 + 0], a10, 0, 0, 0);
          a11 = __builtin_amdgcn_mfma_f32_16x16x32_bf16(af, wf[q * 2 + 1], a11, 0, 0, 0);
        }
      }
    }
#pragma unroll
    for (int r = 0; r < 4; ++r) {
      smG[kh][g][grp * 4 + r][lo16] = a00[r];
      smG[kh][g][grp * 4 + r][16 + lo16] = a01[r];
      smG[kh][g][16 + grp * 4 + r][lo16] = a10[r];
      smG[kh][g][16 + grp * 4 + r][16 + lo16] = a11[r];
    }
    __syncthreads();

    // elementwise LSTM for (row, c0) and (row, c0+1)
    const float dl0 = s_dl0[row];
    const bool valid = t < len;
    float z[4][2];
#pragma unroll
    for (int gg = 0; gg < 4; ++gg) {
#pragma unroll
      for (int jj = 0; jj < 2; ++jj)
        z[gg][jj] = smG[0][gg][row][c0 + jj] + smG[1][gg][row][c0 + jj] + eg[gg][jj]
                  + dl0 * wD[gg][jj] + (valid ? wV[gg][jj] : 0.f) + wB[gg][jj];
    }
    float gam0 = sigm(dl0 * dW0 + dB0), gam1 = sigm(dl0 * dW1 + dB1);
    float nc0 = sigm(z[1][0]) * cc0 + sigm(z[0][0]) * tanh_f(z[2][0]);
    float nc1 = sigm(z[1][1]) * cc1 + sigm(z[0][1]) * tanh_f(z[2][1]);
    float nh0 = sigm(z[3][0]) * tanh_f(nc0);
    float nh1 = sigm(z[3][1]) * tanh_f(nc1);
    float hn0 = valid ? nh0 : hh0 * gam0;
    float hn1 = valid ? nh1 : hh1 * gam1;
    cc0 = valid ? nc0 : cc0;  cc1 = valid ? nc1 : cc1;
    hh0 = hn0;  hh1 = hn1;

    if (t < 511) {
      const float dl1 = s_dl1[row];
      float p0 = hn0 * sigm(dl1 * dW0 + dB0);
      float p1 = hn1 * sigm(dl1 * dW1 + dB1);
      unsigned short u0 = __builtin_bit_cast(unsigned short, (bf16)p0);
      unsigned short u1 = __builtin_bit_cast(unsigned short, (bf16)p1);
      unsigned uval = (unsigned)u0 | ((unsigned)u1 << 16);
      char* dst = (char*)hwrite + (size_t)(b0 + row) * 2048 + (size_t)(n0 + c0) * 2;
      asm volatile("global_store_dword %0, %1, off sc0 sc1" :: "v"(dst), "v"(uval) : "memory");
      asm volatile("s_waitcnt vmcnt(0)" ::: "memory");
      __syncthreads();   // all waves' h-stores are at the coherence point
      if (tid == 0) {
        int* fdst = grpflags + ng;
        int fval = t + 1;
        asm volatile("global_store_dword %0, %1, off sc0 sc1" :: "v"(fdst), "v"(fval) : "memory");
      }
      if (tid < 64) {
        const int* fp = grpflags + (tid & 31);
        const int tgt = t + 1;
        while (true) {
          int v = __hip_atomic_load(fp, __ATOMIC_RELAXED, __HIP_MEMORY_SCOPE_AGENT);
          if (__all(v >= tgt)) break;
          __builtin_amdgcn_s_sleep(1);
        }
      }
      __syncthreads();
    } else {
      float* dst = hstate + (size_t)(b0 + row) * 1024 + n0 + c0;
      dst[0] = hn0; dst[1] = hn1;
    }
  }
}

// ---------------- host -------------------------------------------------------
extern "C" void kernel_launch(void* const* d_in, const int* in_sizes, int n_in,
                              void* d_out, int out_size, void* d_ws, size_t ws_size,
                              hipStream_t stream) {
  const int*   labels = (const int*)d_in[0];
  const float* deltas = (const float*)d_in[1];
  const int*   lengths= (const int*)d_in[2];
  const float* statef = (const float*)d_in[3];
  const float* emb    = (const float*)d_in[4];
  const float* projW  = (const float*)d_in[5];
  const float* projb  = (const float*)d_in[6];
  const float* decW   = (const float*)d_in[7];
  const float* decb   = (const float*)d_in[8];
  const float* wih    = (const float*)d_in[9];
  const float* whh    = (const float*)d_in[10];
  const float* bih    = (const float*)d_in[11];
  const float* bhh    = (const float*)d_in[12];
  const float* sh1W   = (const float*)d_in[13];
  const float* sh1b   = (const float*)d_in[14];
  const float* sh2W   = (const float*)d_in[15];
  const float* sh2b   = (const float*)d_in[16];
  const float* labW   = (const float*)d_in[17];
  const float* labb   = (const float*)d_in[18];
  const float* delW   = (const float*)d_in[19];
  const float* delb   = (const float*)d_in[20];

  char* ws = (char*)d_ws;
  size_t off = 0;
  auto alloc = [&](size_t bytes) -> void* {
    void* p = ws + off;
    off += (bytes + 1023) & ~(size_t)1023;
    return p;
  };
  bf16*  emb_bf  = (bf16*)alloc((size_t)10000 * 512 * 2);
  bf16*  projT   = (bf16*)alloc((size_t)515 * 1024 * 2);
  bf16*  wih_bf  = (bf16*)alloc((size_t)4096 * 1024 * 2);
  float* wfused  = (float*)alloc((size_t)4096 * 520 * 4);
  bf16*  wfe     = (bf16*)alloc((size_t)4096 * 512 * 2);
  float* wfD     = (float*)alloc(4096 * 4);
  float* wfV     = (float*)alloc(4096 * 4);
  float* bias4   = (float*)alloc(4096 * 4);
  bf16*  embg    = (bf16*)alloc((size_t)10000 * 4096 * 2);
  bf16*  warr    = (bf16*)alloc((size_t)4096 * 1024 * 2);
  bf16*  hpre0   = (bf16*)alloc((size_t)256 * 1024 * 2);
  bf16*  hpre1   = (bf16*)alloc((size_t)256 * 1024 * 2);
  float* hstate  = (float*)alloc((size_t)256 * 1024 * 4);
  float* dlogb   = (float*)alloc((size_t)256 * 512 * 4);
  bf16*  tin     = (bf16*)alloc((size_t)256 * 1088 * 2);
  bf16*  t1      = (bf16*)alloc((size_t)256 * 1024 * 2);
  bf16*  t2      = (bf16*)alloc((size_t)256 * 1024 * 2);
  bf16*  sh1w_bf = (bf16*)alloc((size_t)1024 * 1088 * 2);
  bf16*  sh2w_bf = (bf16*)alloc((size_t)1024 * 1024 * 2);
  bf16*  labw_bf = (bf16*)alloc((size_t)10000 * 1024 * 2);
  int*   flags   = (int*)alloc(2048);

  if (off > ws_size) {
    sentinel<<<1, 1, 0, stream>>>((float*)d_out);
    return;
  }

  conv_bf<<<(5120000 + 255) / 256, 256, 0, stream>>>(emb, emb_bf, 5120000);
  build_projT<<<(515 * 1024 + 255) / 256, 256, 0, stream>>>(projW, projb, projT);
  conv_bf<<<(4194304 + 255) / 256, 256, 0, stream>>>(wih, wih_bf, 4194304);
  dlog_prep<<<(131072 + 255) / 256, 256, 0, stream>>>(deltas, dlogb, 131072);
  gemm_bt<false, false, false><<<dim3(32, 5), 256, 0, stream>>>(
      wih_bf, 1024, projT, 1024, (void*)wfused, 520, nullptr, 4096, 515, 1024);
  wf_split<<<16, 256, 0, stream>>>(wfused, bih, bhh, wfD, wfV, bias4);
  wfe_conv<<<(4096 * 512 + 255) / 256, 256, 0, stream>>>(wfused, wfe);
  gemm_bt<true, false, false><<<dim3(79, 32), 256, 0, stream>>>(
      emb_bf, 512, wfe, 512, (void*)embg, 4096, nullptr, 10000, 4096, 512);
  prep_warr<<<(524288 + 255) / 256, 256, 0, stream>>>(whh, warr);
  conv_bf<<<(1114112 + 255) / 256, 256, 0, stream>>>(sh1W, sh1w_bf, 1114112);
  conv_bf<<<(1048576 + 255) / 256, 256, 0, stream>>>(sh2W, sh2w_bf, 1048576);
  conv_bf<<<(10240000 + 255) / 256, 256, 0, stream>>>(labW, labw_bf, 10240000);

  hipMemsetAsync(flags, 0, 2048, stream);
  scan_kernel<<<256, 512, 0, stream>>>(embg, warr, wfD, wfV, bias4,
                                       labels, dlogb, lengths, decW, decb,
                                       hpre0, hpre1, hstate, flags);

  build_tin<<<(256 * 1088 + 255) / 256, 256, 0, stream>>>(hstate, statef, tin);
  gemm_bt<true, true, true><<<dim3(2, 8), 256, 0, stream>>>(
      tin, 1088, sh1w_bf, 1088, (void*)t1, 1024, sh1b, 256, 1024, 1088);
  gemm_bt<true, true, true><<<dim3(2, 8), 256, 0, stream>>>(
      t1, 1024, sh2w_bf, 1024, (void*)t2, 1024, sh2b, 256, 1024, 1024);
  gemm_bt<false, false, true><<<dim3(2, 79), 256, 0, stream>>>(
      t2, 1024, labw_bf, 1024, d_out, 10000, labb, 256, 10000, 1024);
  delta_head<<<1, 256, 0, stream>>>(t2, delW, delb, (float*)d_out + 2560000);
}